// Round 1
// 1560.458 us; speedup vs baseline: 1.8733x; 1.8733x over previous
//
#include <hip/hip_runtime.h>
#include <hip/hip_bf16.h>
#include <stdint.h>

// Problem constants
#define BATCH   65536
#define CHUNK_B 32768
#define INDIM   512
#define HDIM    512
#define H3      1536
#define NHEAD   8
#define HEADD   64

typedef __attribute__((ext_vector_type(4))) float  f32x4;
typedef __attribute__((ext_vector_type(8))) __bf16 bf16x8;
typedef __attribute__((ext_vector_type(4))) __bf16 bf16x4;

// async global->LDS, 16B per lane. LDS dest must be linear in lane order (wave-uniform base + lane*16).
__device__ __forceinline__ void gl_lds16(const void* g, void* l) {
  __builtin_amdgcn_global_load_lds(
      (const __attribute__((address_space(1))) unsigned int*)g,
      (__attribute__((address_space(3))) unsigned int*)l, 16, 0, 0);
}

// ---------------- prep: f32 -> bf16 (plain) ----------------
__global__ void convert_kernel(const float* __restrict__ s, __bf16* __restrict__ d, int n4) {
  int i = blockIdx.x * blockDim.x + threadIdx.x;
  int stride = gridDim.x * blockDim.x;
  for (; i < n4; i += stride) {
    float4 v = ((const float4*)s)[i];
    bf16x4 o = {(__bf16)v.x, (__bf16)v.y, (__bf16)v.z, (__bf16)v.w};
    ((bf16x4*)d)[i] = o;
  }
}

// ---------------- prep: Wqkv f32 -> bf16, reordered head-major ----------------
// src row r (of 1536): sec = r/512 (q,k,v), hd = (r%512)/64, w = r%64
// dst row r' = hd*192 + sec*64 + w   (so each head's 192 rows are contiguous: q|k|v)
__global__ void convert_qkv_kernel(const float* __restrict__ s, __bf16* __restrict__ d) {
  int i = blockIdx.x * blockDim.x + threadIdx.x;  // float4 units, 1536*512/4 = 196608
  if (i < 196608) {
    int row = i >> 7, c4 = (i & 127) << 2;
    int sec = row >> 9, rr = row & 511;
    int hd = rr >> 6, w = rr & 63;
    int rp = hd * 192 + sec * 64 + w;
    float4 v = ((const float4*)s)[i];
    bf16x4 o = {(__bf16)v.x, (__bf16)v.y, (__bf16)v.z, (__bf16)v.w};
    *(bf16x4*)&d[(size_t)rp * 512 + c4] = o;
  }
}

// ---------------- GEMM1: h_pre[m,n] = x[m,:] . W_fc[n,:] + b_fc[n] ----------------
// 128x128 tile, BK=32, 256 threads, mfma 16x16x32 bf16. XOR-swizzled LDS (16B chunk ^ row&3).
__global__ __launch_bounds__(256) void gemm1_kernel(
    const float* __restrict__ x, const __bf16* __restrict__ Wfc,
    const float* __restrict__ bfc, __bf16* __restrict__ hpre)
{
  __shared__ __align__(16) __bf16 sA[128 * 32];
  __shared__ __align__(16) __bf16 sB[128 * 32];
  const int tid  = threadIdx.x;
  const int wave = tid >> 6, lane = tid & 63;
  const int wm = wave >> 1, wn = wave & 1;
  const int lrow = lane & 15, quad = lane >> 4;
  const int m0 = blockIdx.y * 128, n0 = blockIdx.x * 128;

  f32x4 acc[4][4] = {};

  for (int k0 = 0; k0 < 512; k0 += 32) {
    __syncthreads();
    // A: x fp32 -> bf16, dest-swizzled ds_write (8B units)
    {
      const float* xb = x + (size_t)m0 * 512 + k0;
      #pragma unroll
      for (int i = 0; i < 4; i++) {
        int slot = i * 256 + tid;
        int row = slot >> 3, s8 = slot & 7;
        float4 v = *(const float4*)&xb[(size_t)row * 512 + s8 * 4];
        bf16x4 o = {(__bf16)v.x, (__bf16)v.y, (__bf16)v.z, (__bf16)v.w};
        int ch = (s8 >> 1) ^ (row & 3);
        *(bf16x4*)&sA[row * 32 + ch * 8 + (s8 & 1) * 4] = o;
      }
    }
    // B: W_fc bf16, source-swizzled gl_lds16 (linear LDS dest)
    {
      const __bf16* Wb = Wfc + (size_t)n0 * 512 + k0;
      int row = tid >> 2, c = tid & 3;
      int ch = (c ^ (row & 3)) << 3;
      gl_lds16(Wb + (size_t)row * 512 + ch,        &sB[row * 32 + c * 8]);
      gl_lds16(Wb + (size_t)(row + 64) * 512 + ch, &sB[(row + 64) * 32 + c * 8]);
    }
    __syncthreads();
    bf16x8 af[4], bfr[4];
    int ch = (quad ^ (lrow & 3)) << 3;
    #pragma unroll
    for (int i = 0; i < 4; i++) af[i]  = *(bf16x8*)&sA[(wm * 64 + i * 16 + lrow) * 32 + ch];
    #pragma unroll
    for (int j = 0; j < 4; j++) bfr[j] = *(bf16x8*)&sB[(wn * 64 + j * 16 + lrow) * 32 + ch];
    #pragma unroll
    for (int i = 0; i < 4; i++)
      #pragma unroll
      for (int j = 0; j < 4; j++)
        acc[i][j] = __builtin_amdgcn_mfma_f32_16x16x32_bf16(af[i], bfr[j], acc[i][j], 0, 0, 0);
  }

  #pragma unroll
  for (int i = 0; i < 4; i++) {
    int gm = m0 + wm * 64 + i * 16 + quad * 4;
    #pragma unroll
    for (int j = 0; j < 4; j++) {
      int gn = n0 + wn * 64 + j * 16 + lrow;
      float bv = bfc[gn];
      #pragma unroll
      for (int r = 0; r < 4; r++)
        hpre[(size_t)(gm + r) * H3 + gn] = (__bf16)(acc[i][j][r] + bv);
    }
  }
}

// ---------------- LayerNorm(1536) + ReLU, in place (bf16) ----------------
__global__ __launch_bounds__(256) void ln_relu_kernel(
    __bf16* __restrict__ h, const float* __restrict__ g, const float* __restrict__ bta)
{
  int row  = blockIdx.x * 4 + (threadIdx.x >> 6);
  int lane = threadIdx.x & 63;
  __bf16* hr = h + (size_t)row * H3;
  float v[24];
  float s1 = 0.f, s2 = 0.f;
  #pragma unroll
  for (int i = 0; i < 3; i++) {
    bf16x8 x8 = *(bf16x8*)&hr[i * 512 + lane * 8];
    #pragma unroll
    for (int j = 0; j < 8; j++) { float f = (float)x8[j]; v[i * 8 + j] = f; s1 += f; s2 += f * f; }
  }
  #pragma unroll
  for (int off = 32; off > 0; off >>= 1) { s1 += __shfl_down(s1, off, 64); s2 += __shfl_down(s2, off, 64); }
  s1 = __shfl(s1, 0, 64); s2 = __shfl(s2, 0, 64);
  float mu = s1 * (1.f / 1536.f);
  float rs = rsqrtf(s2 * (1.f / 1536.f) - mu * mu + 1e-5f);
  #pragma unroll
  for (int i = 0; i < 3; i++) {
    int c0 = i * 512 + lane * 8;
    bf16x8 o;
    #pragma unroll
    for (int j = 0; j < 8; j++) {
      float val = (v[i * 8 + j] - mu) * rs * g[c0 + j] + bta[c0 + j];
      o[j] = (__bf16)fmaxf(val, 0.f);
    }
    *(bf16x8*)&hr[c0] = o;
  }
}

// ---------------- Kernel A: qkv GEMM (one head) + attention -> ctx ----------------
// grid: 8192 blocks (8 heads x 1024 groups of 32 batches = 96 token rows).
// Decode keeps all 8 head-blocks of one group on the SAME XCD (p%8 == grp%8) and
// temporally adjacent, so the shared h rows are L2 hits.
__global__ __launch_bounds__(256) void qkv_attn_kernel(
    const __bf16* __restrict__ h,     // [3*CHUNK_B, 512]
    const __bf16* __restrict__ Wr,    // [1536, 512] head-major reordered
    const float*  __restrict__ bqkv,  // [1536] original layout
    __bf16* __restrict__ ctx)         // [3*CHUNK_B, 512]
{
  __shared__ __align__(16) char pool[39936];
  __bf16* sA   = (__bf16*)pool;            // [96][64]   12288 B (GEMM phase)
  __bf16* sW   = (__bf16*)(pool + 12288);  // [192][64]  24576 B (GEMM phase)
  __bf16* sQKV = (__bf16*)pool;            // [96][200]  38400 B (attn phase, padded)
  float*  sS   = (float*)(pool + 38400);   // [32][12]    1536 B

  const int tid  = threadIdx.x;
  const int wave = tid >> 6, lane = tid & 63;
  const int lrow = lane & 15, quad = lane >> 4;
  const int wm = wave >> 1, wn = wave & 1;
  const int p   = blockIdx.x;
  const int hd  = (p >> 3) & 7;
  const int grp = ((p >> 6) << 3) | (p & 7);
  const size_t R0 = (size_t)grp * 96;

  f32x4 qacc[3][6] = {};

  for (int k0 = 0; k0 < 512; k0 += 64) {
    __syncthreads();
    // A: h rows R0..R0+95, source-swizzled, linear LDS dest
    #pragma unroll
    for (int s = 0; s < 3; s++) {
      int slot = s * 256 + tid;
      int row = slot >> 3, c = slot & 7;
      gl_lds16(h + (R0 + row) * 512 + k0 + ((c ^ (row & 7)) << 3), &sA[slot << 3]);
    }
    // W: head hd's 192 rows (contiguous in Wr)
    #pragma unroll
    for (int s = 0; s < 6; s++) {
      int slot = s * 256 + tid;
      int row = slot >> 3, c = slot & 7;
      gl_lds16(Wr + (size_t)(hd * 192 + row) * 512 + k0 + ((c ^ (row & 7)) << 3), &sW[slot << 3]);
    }
    __syncthreads();
    #pragma unroll
    for (int kk = 0; kk < 2; kk++) {
      int ch = (((kk << 2) | quad) ^ (lrow & 7)) << 3;
      bf16x8 af[3], bf[6];
      #pragma unroll
      for (int i = 0; i < 3; i++) af[i] = *(bf16x8*)&sA[(wm * 48 + i * 16 + lrow) * 64 + ch];
      #pragma unroll
      for (int j = 0; j < 6; j++) bf[j] = *(bf16x8*)&sW[(wn * 96 + j * 16 + lrow) * 64 + ch];
      #pragma unroll
      for (int i = 0; i < 3; i++)
        #pragma unroll
        for (int j = 0; j < 6; j++)
          qacc[i][j] = __builtin_amdgcn_mfma_f32_16x16x32_bf16(af[i], bf[j], qacc[i][j], 0, 0, 0);
    }
  }
  __syncthreads();

  // qkv (+bias) -> LDS, padded stride 200
  #pragma unroll
  for (int j = 0; j < 6; j++) {
    int col = wn * 96 + j * 16 + lrow;
    int sec = col >> 6, w = col & 63;
    float bv = bqkv[sec * 512 + hd * 64 + w];
    #pragma unroll
    for (int i = 0; i < 3; i++) {
      int row = wm * 48 + i * 16 + quad * 4;
      #pragma unroll
      for (int r = 0; r < 4; r++)
        sQKV[(row + r) * 200 + col] = (__bf16)(qacc[i][j][r] + bv);
    }
  }
  __syncthreads();

  // scores: 32 batches x 9 (qt,kt) pairs
  for (int t = tid; t < 288; t += 256) {
    int bi = t / 9, r9 = t - bi * 9;
    int qt = r9 / 3, kt = r9 - qt * 3;
    const __bf16* qv = &sQKV[(bi * 3 + qt) * 200];
    const __bf16* kv = &sQKV[(bi * 3 + kt) * 200 + 64];
    float s = 0.f;
    #pragma unroll
    for (int d8 = 0; d8 < 8; d8++) {
      bf16x8 q8 = *(bf16x8*)&qv[d8 * 8];
      bf16x8 k8 = *(bf16x8*)&kv[d8 * 8];
      #pragma unroll
      for (int u = 0; u < 8; u++) s += (float)q8[u] * (float)k8[u];
    }
    sS[bi * 12 + r9] = s * 0.125f;
  }
  __syncthreads();
  // softmax over kt per (batch, qt)
  if (tid < 96) {
    int bi = tid / 3, qt = tid - bi * 3;
    float* sp = &sS[bi * 12 + qt * 3];
    float a0 = sp[0], a1 = sp[1], a2 = sp[2];
    float mx = fmaxf(a0, fmaxf(a1, a2));
    float e0 = __expf(a0 - mx), e1 = __expf(a1 - mx), e2 = __expf(a2 - mx);
    float inv = 1.f / (e0 + e1 + e2);
    sp[0] = e0 * inv; sp[1] = e1 * inv; sp[2] = e2 * inv;
  }
  __syncthreads();
  // PV + store ctx[row, hd*64 + d]
  #pragma unroll
  for (int s = 0; s < 3; s++) {
    int t = s * 256 + tid;
    int row = t >> 3, c = t & 7;
    int bi = row / 3, qt = row - bi * 3;
    const float* pp = &sS[bi * 12 + qt * 3];
    float p0 = pp[0], p1 = pp[1], p2 = pp[2];
    bf16x8 v0 = *(bf16x8*)&sQKV[(bi * 3 + 0) * 200 + 128 + c * 8];
    bf16x8 v1 = *(bf16x8*)&sQKV[(bi * 3 + 1) * 200 + 128 + c * 8];
    bf16x8 v2 = *(bf16x8*)&sQKV[(bi * 3 + 2) * 200 + 128 + c * 8];
    bf16x8 o;
    #pragma unroll
    for (int u = 0; u < 8; u++)
      o[u] = (__bf16)(p0 * (float)v0[u] + p1 * (float)v1[u] + p2 * (float)v2[u]);
    *(bf16x8*)&ctx[(R0 + row) * 512 + hd * 64 + c * 8] = o;
  }
}

// ---------------- Kernel B: GEMM3 (ctx @ Wo.T + bo) + gumbel-softmax ----------------
// 96x128 tile (32 full batches), K=512, BK=64. grid: 4096 (4 nblocks x 1024 groups),
// decoded so the 4 n-blocks of one group share an XCD.
__global__ __launch_bounds__(256) void out_kernel(
    const __bf16* __restrict__ ctx, const __bf16* __restrict__ Wo,
    const float* __restrict__ bo, const float* __restrict__ gum,
    float* __restrict__ out, int b0)
{
  __shared__ __align__(16) char pool[49920];
  __bf16* sA   = (__bf16*)pool;            // [96][64]  12288 B
  __bf16* sW   = (__bf16*)(pool + 12288);  // [128][64] 16384 B
  float*  sOut = (float*)pool;             // [96][130] 49920 B (epilogue)

  const int tid  = threadIdx.x;
  const int wave = tid >> 6, lane = tid & 63;
  const int lrow = lane & 15, quad = lane >> 4;
  const int wm = wave >> 1, wn = wave & 1;
  const int p = blockIdx.x;
  const int q = p >> 3;
  const int nb = q & 3;
  const int grp = ((q >> 2) << 3) | (p & 7);
  const int n0 = nb * 128;
  const size_t R0 = (size_t)grp * 96;
  const int bi0 = grp * 32;

  f32x4 acc[3][4] = {};

  for (int k0 = 0; k0 < 512; k0 += 64) {
    __syncthreads();
    #pragma unroll
    for (int s = 0; s < 3; s++) {
      int slot = s * 256 + tid;
      int row = slot >> 3, c = slot & 7;
      gl_lds16(ctx + (R0 + row) * 512 + k0 + ((c ^ (row & 7)) << 3), &sA[slot << 3]);
    }
    #pragma unroll
    for (int s = 0; s < 4; s++) {
      int slot = s * 256 + tid;
      int row = slot >> 3, c = slot & 7;
      gl_lds16(Wo + (size_t)(n0 + row) * 512 + k0 + ((c ^ (row & 7)) << 3), &sW[slot << 3]);
    }
    __syncthreads();
    #pragma unroll
    for (int kk = 0; kk < 2; kk++) {
      int ch = (((kk << 2) | quad) ^ (lrow & 7)) << 3;
      bf16x8 af[3], bf[4];
      #pragma unroll
      for (int i = 0; i < 3; i++) af[i] = *(bf16x8*)&sA[(wm * 48 + i * 16 + lrow) * 64 + ch];
      #pragma unroll
      for (int j = 0; j < 4; j++) bf[j] = *(bf16x8*)&sW[(wn * 64 + j * 16 + lrow) * 64 + ch];
      #pragma unroll
      for (int i = 0; i < 3; i++)
        #pragma unroll
        for (int j = 0; j < 4; j++)
          acc[i][j] = __builtin_amdgcn_mfma_f32_16x16x32_bf16(af[i], bf[j], acc[i][j], 0, 0, 0);
    }
  }
  __syncthreads();

  // acc (+bo) -> padded LDS
  #pragma unroll
  for (int j = 0; j < 4; j++) {
    int col = wn * 64 + j * 16 + lrow;
    float bv = bo[n0 + col];
    #pragma unroll
    for (int i = 0; i < 3; i++) {
      int row = wm * 48 + i * 16 + quad * 4;
      #pragma unroll
      for (int r = 0; r < 4; r++)
        sOut[(row + r) * 130 + col] = acc[i][j][r] + bv;
    }
  }
  __syncthreads();

  // gumbel + softmax over the 3 tokens, store y0|y1|y2
  #pragma unroll
  for (int s = 0; s < 16; s++) {
    int t = s * 256 + tid;
    int bb = t >> 7, n = t & 127;
    size_t b = (size_t)(b0 + bi0 + bb);
    const float* gg = gum + b * 1536 + n0 + n;
    float a0 = sOut[(3 * bb + 0) * 130 + n] + gg[0];
    float a1 = sOut[(3 * bb + 1) * 130 + n] + gg[512];
    float a2 = sOut[(3 * bb + 2) * 130 + n] + gg[1024];
    float mx = fmaxf(a0, fmaxf(a1, a2));
    float e0 = __expf(a0 - mx), e1 = __expf(a1 - mx), e2 = __expf(a2 - mx);
    float inv = 1.f / (e0 + e1 + e2);
    size_t ob = b * 512 + n0 + n;
    out[ob]                            = e0 * inv;
    out[(size_t)BATCH * 512 + ob]      = e1 * inv;
    out[(size_t)2 * BATCH * 512 + ob]  = e2 * inv;
  }
}

// ---------------- launch ----------------
extern "C" void kernel_launch(void* const* d_in, const int* in_sizes, int n_in,
                              void* d_out, int out_size, void* d_ws, size_t ws_size,
                              hipStream_t stream) {
  const float* x    = (const float*)d_in[0];
  const float* W_fc = (const float*)d_in[1];
  const float* b_fc = (const float*)d_in[2];
  const float* ln_g = (const float*)d_in[3];
  const float* ln_b = (const float*)d_in[4];
  const float* Wqkv = (const float*)d_in[5];
  const float* bqkv = (const float*)d_in[6];
  const float* Wo   = (const float*)d_in[7];
  const float* bo   = (const float*)d_in[8];
  const float* gum  = (const float*)d_in[9];
  float* out = (float*)d_out;

  // workspace layout (total 204,996,608 B = identical to previous proven footprint)
  char* ws = (char*)d_ws;
  __bf16* Wfc_bf  = (__bf16*)(ws);                      // 1,572,864
  __bf16* Wqkv_r  = (__bf16*)(ws + 1572864);            // 1,572,864 (head-major)
  __bf16* Wo_bf   = (__bf16*)(ws + 3145728);            //   524,288
  __bf16* h       = (__bf16*)(ws + 3670016);            // [3*CHUNK_B,512] bf16 = 100,663,296
  __bf16* ctx     = (__bf16*)(ws + 3670016 + 100663296);// [3*CHUNK_B,512] bf16 = 100,663,296

  convert_kernel<<<768, 256, 0, stream>>>(W_fc, Wfc_bf, 196608);
  convert_qkv_kernel<<<768, 256, 0, stream>>>(Wqkv, Wqkv_r);
  convert_kernel<<<256, 256, 0, stream>>>(Wo, Wo_bf, 65536);

  for (int c = 0; c < 2; c++) {
    int b0 = c * CHUNK_B;
    gemm1_kernel<<<dim3(12, 256), 256, 0, stream>>>(x + (size_t)b0 * 512, Wfc_bf, b_fc, h);
    ln_relu_kernel<<<8192, 256, 0, stream>>>(h, ln_g, ln_b);
    qkv_attn_kernel<<<8192, 256, 0, stream>>>(h, Wqkv_r, bqkv, ctx);
    out_kernel<<<4096, 256, 0, stream>>>(ctx, Wo_bf, bo, gum, out, b0);
  }
}